// Round 19
// baseline (459.249 us; speedup 1.0000x reference)
//
#include <hip/hip_runtime.h>
#include <math.h>

#define NN 50000
#define NE 400000
#define NG 128
#define SCAN_B 49   // ceil(NN/1024)

typedef __bf16 bf16x8 __attribute__((ext_vector_type(8)));
typedef float f32x4 __attribute__((ext_vector_type(4)));
typedef _Float16 h16x4 __attribute__((ext_vector_type(4)));

// bijective XCD-chunked swizzle (m204): each XCD gets a contiguous chunk
__device__ __forceinline__ int xcd_swz(int bid, int nwg)
{
    int q = nwg >> 3, r = nwg & 7;
    int xcd = bid & 7, off = bid >> 3;
    return (xcd < r ? xcd * (q + 1) : r * (q + 1) + (xcd - r) * q) + off;
}

// ---------------------------------------------------------------------------
// prep: fused weights Wp1[64,128], Wp2[128,16]; concatenated biases
// ---------------------------------------------------------------------------
__global__ void prep_kernel(const float* __restrict__ Wq1, const float* __restrict__ bq1,
                            const float* __restrict__ bk1, const float* __restrict__ bv1,
                            const float* __restrict__ bs1, const float* __restrict__ We1,
                            const float* __restrict__ Wq2, const float* __restrict__ bq2,
                            const float* __restrict__ bk2, const float* __restrict__ bv2,
                            const float* __restrict__ bs2, const float* __restrict__ We2,
                            float* __restrict__ Wp1, float* __restrict__ Wp2,
                            float* __restrict__ bcat1, float* __restrict__ bcat2)
{
    int idx = blockIdx.x * blockDim.x + threadIdx.x;
    if (idx < 8192) {                       // Wp1[64,128]
        int m = idx >> 7, c = idx & 127;
        int h = c >> 4, d = c & 15;
        float s = 0.f;
        #pragma unroll
        for (int j = 0; j < 16; ++j)
            s += Wq1[m * 128 + h * 16 + j] * We1[d * 128 + h * 16 + j];
        Wp1[idx] = s;
    } else if (idx < 8320) {                // bp1 -> bcat1[512..640)
        int c = idx - 8192;
        int h = c >> 4, d = c & 15;
        float s = 0.f;
        #pragma unroll
        for (int j = 0; j < 16; ++j)
            s += bq1[h * 16 + j] * We1[d * 128 + h * 16 + j];
        bcat1[512 + c] = s;
    } else if (idx < 10368) {               // Wp2[128,16]
        int i = idx - 8320;
        int m = i >> 4, d = i & 15;
        float s = 0.f;
        for (int j = 0; j < 128; ++j)
            s += Wq2[m * 128 + j] * We2[d * 128 + j];
        Wp2[m * 16 + d] = s;
    } else if (idx < 10384) {               // bp2 -> bcat2[512..528)
        int d = idx - 10368;
        float s = 0.f;
        for (int j = 0; j < 128; ++j)
            s += bq2[j] * We2[d * 128 + j];
        bcat2[512 + d] = s;
    } else if (idx < 10896) {               // bcat1[0..512)
        int i = idx - 10384;
        int seg = i >> 7, c = i & 127;
        const float* b = (seg == 0) ? bq1 : (seg == 1) ? bk1 : (seg == 2) ? bv1 : bs1;
        bcat1[i] = b[c];
    } else if (idx < 11408) {               // bcat2[0..512)
        int i = idx - 10896;
        int seg = i >> 7, c = i & 127;
        const float* b = (seg == 0) ? bq2 : (seg == 1) ? bk2 : (seg == 2) ? bv2 : bs2;
        bcat2[i] = b[c];
    }
}

// ---------------------------------------------------------------------------
// pack: MFMA fragment-ready hi/lo bf16 weight blocks.
//   mat0: gemm1 Wcat[64,640]   blocks 0..79
//   mat1: gemm2 Wcat[128,528]  blocks 80..211
//   mat2: gemm3 Wcat[128,256]  blocks 212..275
//   mat3: W1c[16->32pad,128]   blocks 276..283 (for fused eaW in edge_out)
// ---------------------------------------------------------------------------
__global__ void pack_kernel(const float* __restrict__ Wq1, const float* __restrict__ Wk1,
                            const float* __restrict__ Wv1, const float* __restrict__ Ws1,
                            const float* __restrict__ Wp1,
                            const float* __restrict__ Wq2, const float* __restrict__ Wk2,
                            const float* __restrict__ Wv2, const float* __restrict__ Ws2,
                            const float* __restrict__ Wp2,
                            const float* __restrict__ W1,
                            __bf16* __restrict__ pk)
{
    int b = blockIdx.x;
    int mat, kt, ct;
    if (b < 80)       { mat = 0; kt = b / 40;        ct = b % 40; }
    else if (b < 212) { mat = 1; kt = (b - 80) / 33; ct = (b - 80) % 33; }
    else if (b < 276) { mat = 2; kt = (b - 212) / 16; ct = (b - 212) % 16; }
    else              { mat = 3; kt = 0;             ct = b - 276; }
    __bf16* blkp = pk + (size_t)b * 1024;
    for (int item = threadIdx.x; item < 512; item += 256) {
        int lane = item >> 3, j = item & 7;
        int k = kt * 32 + (lane >> 4) * 8 + j;
        int col = ct * 16 + (lane & 15);
        float v;
        if (mat == 0) {
            int seg = col >> 7, cc = col & 127;
            const float* W = (seg == 0) ? Wq1 : (seg == 1) ? Wk1 : (seg == 2) ? Wv1
                             : (seg == 3) ? Ws1 : Wp1;
            v = W[k * 128 + cc];
        } else if (mat == 1) {
            if (col < 512) {
                int seg = col >> 7, cc = col & 127;
                const float* W = (seg == 0) ? Wq2 : (seg == 1) ? Wk2 : (seg == 2) ? Wv2 : Ws2;
                v = W[k * 128 + cc];
            } else {
                v = Wp2[k * 16 + (col - 512)];
            }
        } else if (mat == 2) {
            v = (col < 128) ? W1[k * 128 + col] : W1[(size_t)(128 + k) * 128 + (col - 128)];
        } else {
            v = (k < 16) ? W1[(size_t)(256 + k) * 128 + col] : 0.f;
        }
        __bf16 h = (__bf16)v;
        __bf16 lo = (__bf16)(v - (float)h);
        blkp[lane * 8 + j] = h;
        blkp[512 + lane * 8 + j] = lo;
    }
}

// ---------------------------------------------------------------------------
// CSR build by dst — count, 2-dispatch parallel scan, scatter(+ea copy fused)
// ---------------------------------------------------------------------------
__global__ void count_kernel(const int* __restrict__ dst, int* __restrict__ counts)
{
    int e = blockIdx.x * blockDim.x + threadIdx.x;
    if (e < NE) atomicAdd(&counts[dst[e]], 1);
}

__global__ void scanA_kernel(const int* __restrict__ counts,
                             int* __restrict__ row_start, int* __restrict__ bsum)
{
    __shared__ int lds[1024];
    int t = threadIdx.x, b = blockIdx.x;
    int i = b * 1024 + t;
    int v = (i < NN) ? counts[i] : 0;
    lds[t] = v;
    __syncthreads();
    for (int off = 1; off < 1024; off <<= 1) {
        int u = (t >= off) ? lds[t - off] : 0;
        __syncthreads();
        lds[t] += u;
        __syncthreads();
    }
    if (i < NN) row_start[i] = lds[t] - v;     // block-local exclusive
    if (t == 1023) bsum[b] = lds[1023];
}

// scanC: each block redundantly scans bsum (49 values) in wave 0, then adds
// its own exclusive block offset (merges old scanB into scanC).
__global__ void scanC_kernel(int* __restrict__ row_start, const int* __restrict__ bsum,
                             int* __restrict__ cursor)
{
    __shared__ int boff_s;
    int t = threadIdx.x;
    if (t < 64) {
        int orig = (t < SCAN_B) ? bsum[t] : 0;
        int v = orig;
        #pragma unroll
        for (int off = 1; off < 64; off <<= 1) {
            int u = __shfl_up(v, off, 64);
            if (t >= off) v += u;
        }
        if (t == blockIdx.x) boff_s = v - orig;
    }
    __syncthreads();
    int i = blockIdx.x * 1024 + t;
    if (i < NN) {
        int rs = row_start[i] + boff_s;
        row_start[i] = rs;
        cursor[i] = rs;
    }
    if (i == 0) row_start[NN] = NE;
}

// scatter: CSR placement + ed4/se side arrays + eac copy (ea read is
// sequential in e -> coalesced; eac write is scattered full 64B lines)
__global__ void scatter_kernel(const int* __restrict__ src, const int* __restrict__ dst,
                               const int* __restrict__ batch, const float* __restrict__ ea,
                               int* __restrict__ cursor, int4* __restrict__ ed4,
                               int* __restrict__ se, float* __restrict__ eac)
{
    int e = blockIdx.x * blockDim.x + threadIdx.x;
    if (e < NE) {
        int d = dst[e];
        int s = src[e];
        int p = atomicAdd(&cursor[d], 1);
        ed4[p] = make_int4(e, s, d, batch[s]);
        se[p] = s;
        const float* ap = ea + (size_t)e * 16;
        float4 a0 = *(const float4*)ap;
        float4 a1 = *(const float4*)(ap + 4);
        float4 a2 = *(const float4*)(ap + 8);
        float4 a3 = *(const float4*)(ap + 12);
        float* ep = eac + (size_t)p * 16;
        *(float4*)ep = a0;
        *(float4*)(ep + 4) = a1;
        *(float4*)(ep + 8) = a2;
        *(float4*)(ep + 12) = a3;
    }
}

// ---------------------------------------------------------------------------
// MFMA GEMM, split-bf16 3-term, 2 column-tiles in flight (4 indep acc chains).
// All outputs fp16: cols [CLO,CHI) -> auxh; others -> outh (width OW, remapped)
// Column tiles split across blockIdx.y (NCG groups) for occupancy.
// ---------------------------------------------------------------------------
__device__ __forceinline__ void load_split(const float* ap, bool ok,
                                           bf16x8& hv, bf16x8& lv)
{
    float av[8];
    if (ok) {
        float4 f0 = *(const float4*)ap;
        float4 f1 = *(const float4*)(ap + 4);
        av[0] = f0.x; av[1] = f0.y; av[2] = f0.z; av[3] = f0.w;
        av[4] = f1.x; av[5] = f1.y; av[6] = f1.z; av[7] = f1.w;
    } else {
        #pragma unroll
        for (int j = 0; j < 8; ++j) av[j] = 0.f;
    }
    #pragma unroll
    for (int j = 0; j < 8; ++j) {
        __bf16 h = (__bf16)av[j];
        hv[j] = h;
        lv[j] = (__bf16)(av[j] - (float)h);
    }
}

template<int AUXW, int OW>
__device__ __forceinline__ void gemm_store(int col, int rbase, int kq,
                                           const f32x4& acc0, const f32x4& acc1,
                                           int CLO, int CHI,
                                           _Float16* __restrict__ outh,
                                           _Float16* __restrict__ auxh)
{
    bool inAux = (col >= CLO) && (col < CHI);
    int mcol = (col < CLO) ? col : col - AUXW;
    #pragma unroll
    for (int i = 0; i < 4; ++i) {
        int ra = rbase + kq * 4 + i;
        int rb = ra + 16;
        if (ra < NN) {
            if (inAux) auxh[(size_t)ra * AUXW + (col - CLO)] = (_Float16)acc0[i];
            else if constexpr (OW > 0) outh[(size_t)ra * OW + mcol] = (_Float16)acc0[i];
        }
        if (rb < NN) {
            if (inAux) auxh[(size_t)rb * AUXW + (col - CLO)] = (_Float16)acc1[i];
            else if constexpr (OW > 0) outh[(size_t)rb * OW + mcol] = (_Float16)acc1[i];
        }
    }
}

template<int KD, int NCT, int NCG, bool BIAS, int CLO, int CHI, int OW>
__global__ void mfma_gemm_kernel(const float* __restrict__ A, const __bf16* __restrict__ pk,
                                 const float* __restrict__ bias,
                                 _Float16* __restrict__ outh,
                                 _Float16* __restrict__ auxh)
{
    constexpr int NKT = KD / 32;
    constexpr int AUXW = CHI - CLO;
    constexpr int CPG = (NCT + NCG - 1) / NCG;
    int cg = blockIdx.y;
    int ct0 = cg * CPG;
    int ct1 = (ct0 + CPG < NCT) ? ct0 + CPG : NCT;
    int t = threadIdx.x, w = t >> 6, l = t & 63;
    int rbase = blockIdx.x * 128 + w * 32;
    int lr = l & 15, kq = l >> 4;
    int r0 = rbase + lr, r1 = rbase + 16 + lr;
    bool ok0 = r0 < NN, ok1 = r1 < NN;
    bf16x8 ah0[NKT], al0[NKT], ah1[NKT], al1[NKT];
    #pragma unroll
    for (int kt = 0; kt < NKT; ++kt) {
        load_split(A + (size_t)r0 * KD + kt * 32 + kq * 8, ok0, ah0[kt], al0[kt]);
        load_split(A + (size_t)r1 * KD + kt * 32 + kq * 8, ok1, ah1[kt], al1[kt]);
    }
    int ct = ct0;
    for (; ct + 1 < ct1; ct += 2) {
        float ba = BIAS ? bias[ct * 16 + lr] : 0.f;
        float bb = BIAS ? bias[(ct + 1) * 16 + lr] : 0.f;
        f32x4 accA0 = {ba, ba, ba, ba};
        f32x4 accA1 = {ba, ba, ba, ba};
        f32x4 accB0 = {bb, bb, bb, bb};
        f32x4 accB1 = {bb, bb, bb, bb};
        const __bf16* blkA = pk + (size_t)ct * 1024;
        const __bf16* blkB = pk + (size_t)(ct + 1) * 1024;
        #pragma unroll
        for (int kt = 0; kt < NKT; ++kt) {
            bf16x8 bhA = *(const bf16x8*)(blkA + (size_t)kt * NCT * 1024 + l * 8);
            bf16x8 blA = *(const bf16x8*)(blkA + (size_t)kt * NCT * 1024 + 512 + l * 8);
            bf16x8 bhB = *(const bf16x8*)(blkB + (size_t)kt * NCT * 1024 + l * 8);
            bf16x8 blB = *(const bf16x8*)(blkB + (size_t)kt * NCT * 1024 + 512 + l * 8);
            accA0 = __builtin_amdgcn_mfma_f32_16x16x32_bf16(al0[kt], bhA, accA0, 0, 0, 0);
            accA1 = __builtin_amdgcn_mfma_f32_16x16x32_bf16(al1[kt], bhA, accA1, 0, 0, 0);
            accB0 = __builtin_amdgcn_mfma_f32_16x16x32_bf16(al0[kt], bhB, accB0, 0, 0, 0);
            accB1 = __builtin_amdgcn_mfma_f32_16x16x32_bf16(al1[kt], bhB, accB1, 0, 0, 0);
            accA0 = __builtin_amdgcn_mfma_f32_16x16x32_bf16(ah0[kt], blA, accA0, 0, 0, 0);
            accA1 = __builtin_amdgcn_mfma_f32_16x16x32_bf16(ah1[kt], blA, accA1, 0, 0, 0);
            accB0 = __builtin_amdgcn_mfma_f32_16x16x32_bf16(ah0[kt], blB, accB0, 0, 0, 0);
            accB1 = __builtin_amdgcn_mfma_f32_16x16x32_bf16(ah1[kt], blB, accB1, 0, 0, 0);
            accA0 = __builtin_amdgcn_mfma_f32_16x16x32_bf16(ah0[kt], bhA, accA0, 0, 0, 0);
            accA1 = __builtin_amdgcn_mfma_f32_16x16x32_bf16(ah1[kt], bhA, accA1, 0, 0, 0);
            accB0 = __builtin_amdgcn_mfma_f32_16x16x32_bf16(ah0[kt], bhB, accB0, 0, 0, 0);
            accB1 = __builtin_amdgcn_mfma_f32_16x16x32_bf16(ah1[kt], bhB, accB1, 0, 0, 0);
        }
        gemm_store<AUXW, OW>(ct * 16 + lr, rbase, kq, accA0, accA1, CLO, CHI, outh, auxh);
        gemm_store<AUXW, OW>((ct + 1) * 16 + lr, rbase, kq, accB0, accB1, CLO, CHI, outh, auxh);
    }
    if (ct < ct1) {
        float b = BIAS ? bias[ct * 16 + lr] : 0.f;
        f32x4 acc0 = {b, b, b, b};
        f32x4 acc1 = {b, b, b, b};
        const __bf16* blk = pk + (size_t)ct * 1024;
        #pragma unroll
        for (int kt = 0; kt < NKT; ++kt) {
            bf16x8 bh = *(const bf16x8*)(blk + (size_t)kt * NCT * 1024 + l * 8);
            bf16x8 bl = *(const bf16x8*)(blk + (size_t)kt * NCT * 1024 + 512 + l * 8);
            acc0 = __builtin_amdgcn_mfma_f32_16x16x32_bf16(al0[kt], bh, acc0, 0, 0, 0);
            acc1 = __builtin_amdgcn_mfma_f32_16x16x32_bf16(al1[kt], bh, acc1, 0, 0, 0);
            acc0 = __builtin_amdgcn_mfma_f32_16x16x32_bf16(ah0[kt], bl, acc0, 0, 0, 0);
            acc1 = __builtin_amdgcn_mfma_f32_16x16x32_bf16(ah1[kt], bl, acc1, 0, 0, 0);
            acc0 = __builtin_amdgcn_mfma_f32_16x16x32_bf16(ah0[kt], bh, acc0, 0, 0, 0);
            acc1 = __builtin_amdgcn_mfma_f32_16x16x32_bf16(ah1[kt], bh, acc1, 0, 0, 0);
        }
        gemm_store<AUXW, OW>(ct * 16 + lr, rbase, kq, acc0, acc1, CLO, CHI, outh, auxh);
    }
}

// ---------------------------------------------------------------------------
// agg1: wave per node, half-wave per edge, 2-deep edge unroll.
// Lane c owns dims [4c,4c+4); head h = c>>2. QSPh [Q|S|P] fp16 stride 384.
// ---------------------------------------------------------------------------
__global__ void agg1_kernel(const _Float16* __restrict__ QSPh, const _Float16* __restrict__ KVh,
                            const int* __restrict__ row_start,
                            const int* __restrict__ se, const float* __restrict__ eac,
                            const float* __restrict__ We1, float* __restrict__ h1)
{
    __shared__ float we[16 * 128];
    int t = threadIdx.x;
    for (int i = t; i < 2048; i += 256) we[i] = We1[i];
    __syncthreads();
    int bid = xcd_swz(blockIdx.x, gridDim.x);
    int wv = t >> 6, l = t & 63;
    int n = bid * 4 + wv;
    if (n >= NN) return;
    int half = l >> 5, c = l & 31;
    const _Float16* qb = QSPh + (size_t)n * 384;
    h16x4 qh = *(const h16x4*)(qb + 4 * c);
    h16x4 Ph = *(const h16x4*)(qb + 256 + 4 * c);
    float q0 = qh[0], q1 = qh[1], q2 = qh[2], q3 = qh[3];
    float P0 = Ph[0], P1 = Ph[1], P2 = Ph[2], P3 = Ph[3];
    float av0 = 0.f, av1 = 0.f, av2 = 0.f, av3 = 0.f;
    float ae0 = 0.f, ae1 = 0.f, ae2 = 0.f, ae3 = 0.f, denom = 0.f;
    int e0 = row_start[n], e1 = row_start[n + 1];
    int idx = e0 + half;
    int eoff = (c & 3) * 4;
    for (; idx + 2 < e1; idx += 4) {
        int sA = se[idx], sB = se[idx + 2];
        const _Float16* ka = KVh + (size_t)sA * 256;
        const _Float16* kbp = KVh + (size_t)sB * 256;
        h16x4 kA = *(const h16x4*)(ka + 4 * c);
        h16x4 vA = *(const h16x4*)(ka + 128 + 4 * c);
        h16x4 kB = *(const h16x4*)(kbp + 4 * c);
        h16x4 vB = *(const h16x4*)(kbp + 128 + 4 * c);
        float4 eA = *(const float4*)(eac + (size_t)idx * 16 + eoff);
        float4 eB = *(const float4*)(eac + (size_t)(idx + 2) * 16 + eoff);
        float pa = q0 * (float)kA[0] + q1 * (float)kA[1]
                 + q2 * (float)kA[2] + q3 * (float)kA[3]
                 + P0 * eA.x + P1 * eA.y + P2 * eA.z + P3 * eA.w;
        float pb = q0 * (float)kB[0] + q1 * (float)kB[1]
                 + q2 * (float)kB[2] + q3 * (float)kB[3]
                 + P0 * eB.x + P1 * eB.y + P2 * eB.z + P3 * eB.w;
        pa += __shfl_xor(pa, 1, 64); pb += __shfl_xor(pb, 1, 64);
        pa += __shfl_xor(pa, 2, 64); pb += __shfl_xor(pb, 2, 64);
        float wA = __expf(pa * 0.25f);
        float wB = __expf(pb * 0.25f);
        denom += wA + wB;
        av0 += wA * (float)vA[0] + wB * (float)vB[0];
        av1 += wA * (float)vA[1] + wB * (float)vB[1];
        av2 += wA * (float)vA[2] + wB * (float)vB[2];
        av3 += wA * (float)vA[3] + wB * (float)vB[3];
        ae0 += wA * eA.x + wB * eB.x;
        ae1 += wA * eA.y + wB * eB.y;
        ae2 += wA * eA.z + wB * eB.z;
        ae3 += wA * eA.w + wB * eB.w;
    }
    if (idx < e1) {
        int s = se[idx];
        const _Float16* kb = KVh + (size_t)s * 256;
        h16x4 k4 = *(const h16x4*)(kb + 4 * c);
        h16x4 v4 = *(const h16x4*)(kb + 128 + 4 * c);
        float4 ea4 = *(const float4*)(eac + (size_t)idx * 16 + eoff);
        float part = q0 * (float)k4[0] + q1 * (float)k4[1]
                   + q2 * (float)k4[2] + q3 * (float)k4[3]
                   + P0 * ea4.x + P1 * ea4.y + P2 * ea4.z + P3 * ea4.w;
        part += __shfl_xor(part, 1, 64);
        part += __shfl_xor(part, 2, 64);
        float w = __expf(part * 0.25f);
        denom += w;
        av0 += w * (float)v4[0]; av1 += w * (float)v4[1];
        av2 += w * (float)v4[2]; av3 += w * (float)v4[3];
        ae0 += w * ea4.x; ae1 += w * ea4.y; ae2 += w * ea4.z; ae3 += w * ea4.w;
    }
    denom += __shfl_xor(denom, 32, 64);
    av0 += __shfl_xor(av0, 32, 64); av1 += __shfl_xor(av1, 32, 64);
    av2 += __shfl_xor(av2, 32, 64); av3 += __shfl_xor(av3, 32, 64);
    ae0 += __shfl_xor(ae0, 32, 64); ae1 += __shfl_xor(ae1, 32, 64);
    ae2 += __shfl_xor(ae2, 32, 64); ae3 += __shfl_xor(ae3, 32, 64);
    float inv = (denom > 0.f) ? 1.f / denom : 0.f;
    float es0 = 0.f, es1 = 0.f, es2 = 0.f, es3 = 0.f;
    int gb = l & 60;                               // 4-lane group base (same half)
    #pragma unroll
    for (int dd = 0; dd < 4; ++dd) {
        int srcl = gb + dd;
        float a0 = __shfl(ae0, srcl, 64);
        float a1 = __shfl(ae1, srcl, 64);
        float a2 = __shfl(ae2, srcl, 64);
        float a3 = __shfl(ae3, srcl, 64);
        int d0 = dd * 4;
        float4 w0 = *(const float4*)&we[(d0 + 0) * 128 + 4 * c];
        float4 w1 = *(const float4*)&we[(d0 + 1) * 128 + 4 * c];
        float4 w2 = *(const float4*)&we[(d0 + 2) * 128 + 4 * c];
        float4 w3 = *(const float4*)&we[(d0 + 3) * 128 + 4 * c];
        es0 += a0 * w0.x + a1 * w1.x + a2 * w2.x + a3 * w3.x;
        es1 += a0 * w0.y + a1 * w1.y + a2 * w2.y + a3 * w3.y;
        es2 += a0 * w0.z + a1 * w1.z + a2 * w2.z + a3 * w3.z;
        es3 += a0 * w0.w + a1 * w1.w + a2 * w2.w + a3 * w3.w;
    }
    if (half == 0) {
        h16x4 s4 = *(const h16x4*)(qb + 128 + 4 * c);
        float o0 = (av0 + es0) * inv + (float)s4[0];
        float o1 = (av1 + es1) * inv + (float)s4[1];
        float o2 = (av2 + es2) * inv + (float)s4[2];
        float o3 = (av3 + es3) * inv + (float)s4[3];
        o0 = (o0 > 0.f) ? o0 : 0.01f * o0;
        o1 = (o1 > 0.f) ? o1 : 0.01f * o1;
        o2 = (o2 > 0.f) ? o2 : 0.01f * o2;
        o3 = (o3 > 0.f) ? o3 : 0.01f * o3;
        *(float4*)(h1 + (size_t)n * 128 + 4 * c) = make_float4(o0, o1, o2, o3);
    }
}

// ---------------------------------------------------------------------------
// agg2: wave per node, half-wave per edge, 2-deep edge unroll.
// Lane c owns dims [4c,4c+4). QSPh [Q|S|P2] fp16 stride 272.
// ---------------------------------------------------------------------------
__global__ void agg2_kernel(const _Float16* __restrict__ QSPh, const _Float16* __restrict__ KVh,
                            const int* __restrict__ row_start,
                            const int* __restrict__ se, const float* __restrict__ eac,
                            const float* __restrict__ We2, float* __restrict__ h2)
{
    int bid = xcd_swz(blockIdx.x, gridDim.x);
    int t = threadIdx.x;
    int wv = t >> 6, l = t & 63;
    int n = bid * 4 + wv;
    if (n >= NN) return;
    int half = l >> 5, c = l & 31;
    const _Float16* qb = QSPh + (size_t)n * 272;
    h16x4 qh = *(const h16x4*)(qb + 4 * c);
    float q0 = qh[0], q1 = qh[1], q2 = qh[2], q3 = qh[3];
    float p0 = 0.f, p1 = 0.f, p2 = 0.f, p3 = 0.f;
    if (c < 4) {
        h16x4 ph = *(const h16x4*)(qb + 256 + 4 * c);
        p0 = ph[0]; p1 = ph[1]; p2 = ph[2]; p3 = ph[3];
    }
    float av0 = 0.f, av1 = 0.f, av2 = 0.f, av3 = 0.f;
    float ae0 = 0.f, ae1 = 0.f, ae2 = 0.f, ae3 = 0.f, denom = 0.f;
    int e0 = row_start[n], e1 = row_start[n + 1];
    int idx = e0 + half;
    for (; idx + 2 < e1; idx += 4) {
        int sA = se[idx], sB = se[idx + 2];
        const _Float16* ka = KVh + (size_t)sA * 256;
        const _Float16* kbp = KVh + (size_t)sB * 256;
        h16x4 kA = *(const h16x4*)(ka + 4 * c);
        h16x4 vA = *(const h16x4*)(ka + 128 + 4 * c);
        h16x4 kB = *(const h16x4*)(kbp + 4 * c);
        h16x4 vB = *(const h16x4*)(kbp + 128 + 4 * c);
        float4 eA = (c < 4) ? *(const float4*)(eac + (size_t)idx * 16 + 4 * c)
                            : make_float4(0.f, 0.f, 0.f, 0.f);
        float4 eB = (c < 4) ? *(const float4*)(eac + (size_t)(idx + 2) * 16 + 4 * c)
                            : make_float4(0.f, 0.f, 0.f, 0.f);
        float pa = q0 * (float)kA[0] + q1 * (float)kA[1]
                 + q2 * (float)kA[2] + q3 * (float)kA[3]
                 + p0 * eA.x + p1 * eA.y + p2 * eA.z + p3 * eA.w;
        float pb = q0 * (float)kB[0] + q1 * (float)kB[1]
                 + q2 * (float)kB[2] + q3 * (float)kB[3]
                 + p0 * eB.x + p1 * eB.y + p2 * eB.z + p3 * eB.w;
        pa += __shfl_xor(pa, 1, 64); pb += __shfl_xor(pb, 1, 64);
        pa += __shfl_xor(pa, 2, 64); pb += __shfl_xor(pb, 2, 64);
        pa += __shfl_xor(pa, 4, 64); pb += __shfl_xor(pb, 4, 64);
        pa += __shfl_xor(pa, 8, 64); pb += __shfl_xor(pb, 8, 64);
        pa += __shfl_xor(pa, 16, 64); pb += __shfl_xor(pb, 16, 64);
        float wA = __expf(pa * 0.08838834764831845f);
        float wB = __expf(pb * 0.08838834764831845f);
        denom += wA + wB;
        av0 += wA * (float)vA[0] + wB * (float)vB[0];
        av1 += wA * (float)vA[1] + wB * (float)vB[1];
        av2 += wA * (float)vA[2] + wB * (float)vB[2];
        av3 += wA * (float)vA[3] + wB * (float)vB[3];
        ae0 += wA * eA.x + wB * eB.x;
        ae1 += wA * eA.y + wB * eB.y;
        ae2 += wA * eA.z + wB * eB.z;
        ae3 += wA * eA.w + wB * eB.w;
    }
    if (idx < e1) {
        int s = se[idx];
        const _Float16* kb = KVh + (size_t)s * 256;
        h16x4 k4 = *(const h16x4*)(kb + 4 * c);
        h16x4 v4 = *(const h16x4*)(kb + 128 + 4 * c);
        float4 ea4 = (c < 4) ? *(const float4*)(eac + (size_t)idx * 16 + 4 * c)
                             : make_float4(0.f, 0.f, 0.f, 0.f);
        float part = q0 * (float)k4[0] + q1 * (float)k4[1]
                   + q2 * (float)k4[2] + q3 * (float)k4[3]
                   + p0 * ea4.x + p1 * ea4.y + p2 * ea4.z + p3 * ea4.w;
        part += __shfl_xor(part, 1, 64);
        part += __shfl_xor(part, 2, 64);
        part += __shfl_xor(part, 4, 64);
        part += __shfl_xor(part, 8, 64);
        part += __shfl_xor(part, 16, 64);
        float w = __expf(part * 0.08838834764831845f);
        denom += w;
        av0 += w * (float)v4[0]; av1 += w * (float)v4[1];
        av2 += w * (float)v4[2]; av3 += w * (float)v4[3];
        ae0 += w * ea4.x; ae1 += w * ea4.y; ae2 += w * ea4.z; ae3 += w * ea4.w;
    }
    denom += __shfl_xor(denom, 32, 64);
    av0 += __shfl_xor(av0, 32, 64); av1 += __shfl_xor(av1, 32, 64);
    av2 += __shfl_xor(av2, 32, 64); av3 += __shfl_xor(av3, 32, 64);
    ae0 += __shfl_xor(ae0, 32, 64); ae1 += __shfl_xor(ae1, 32, 64);
    ae2 += __shfl_xor(ae2, 32, 64); ae3 += __shfl_xor(ae3, 32, 64);
    float inv = (denom > 0.f) ? 1.f / denom : 0.f;
    float t0 = 0.f, t1 = 0.f, t2 = 0.f, t3 = 0.f;
    #pragma unroll
    for (int dd = 0; dd < 4; ++dd) {
        float a0 = __shfl(ae0, dd, 64);
        float a1 = __shfl(ae1, dd, 64);
        float a2 = __shfl(ae2, dd, 64);
        float a3 = __shfl(ae3, dd, 64);
        int d0 = dd * 4;
        float4 w0 = *(const float4*)(We2 + (size_t)(d0 + 0) * 128 + 4 * c);
        float4 w1 = *(const float4*)(We2 + (size_t)(d0 + 1) * 128 + 4 * c);
        float4 w2 = *(const float4*)(We2 + (size_t)(d0 + 2) * 128 + 4 * c);
        float4 w3 = *(const float4*)(We2 + (size_t)(d0 + 3) * 128 + 4 * c);
        t0 += a0 * w0.x + a1 * w1.x + a2 * w2.x + a3 * w3.x;
        t1 += a0 * w0.y + a1 * w1.y + a2 * w2.y + a3 * w3.y;
        t2 += a0 * w0.z + a1 * w1.z + a2 * w2.z + a3 * w3.z;
        t3 += a0 * w0.w + a1 * w1.w + a2 * w2.w + a3 * w3.w;
    }
    if (half == 0) {
        h16x4 s4 = *(const h16x4*)(qb + 128 + 4 * c);
        float o0 = (av0 + t0) * inv + (float)s4[0];
        float o1 = (av1 + t1) * inv + (float)s4[1];
        float o2 = (av2 + t2) * inv + (float)s4[2];
        float o3 = (av3 + t3) * inv + (float)s4[3];
        *(float4*)(h2 + (size_t)n * 128 + 4 * c) = make_float4(o0, o1, o2, o3);
    }
}

// ---------------------------------------------------------------------------
// pooling: sorted batch -> register-accumulated flushes
// ---------------------------------------------------------------------------
__global__ void pool_kernel(const float* __restrict__ h2, const int* __restrict__ batch,
                            float* __restrict__ sums, float* __restrict__ cnt)
{
    int t = threadIdx.x;
    int c = t & 127, half = t >> 7;
    int n0 = blockIdx.x * 64;
    float acc = 0.f, cacc = 0.f;
    int curg = -1;
    for (int r = half; r < 64; r += 2) {
        int n = n0 + r;
        if (n >= NN) break;
        int g = batch[n];
        if (g != curg) {
            if (curg >= 0) {
                atomicAdd(&sums[curg * 128 + c], acc);
                if (c == 0) atomicAdd(&cnt[curg], cacc);
            }
            curg = g; acc = 0.f; cacc = 0.f;
        }
        acc += h2[(size_t)n * 128 + c];
        cacc += 1.f;
    }
    if (curg >= 0) {
        atomicAdd(&sums[curg * 128 + c], acc);
        if (c == 0) atomicAdd(&cnt[curg], cacc);
    }
}

// Gp[g,c] = b1[c] + sum_m pool[g,m] * W1[272+m, c]
__global__ void gp_kernel(const float* __restrict__ sums, const float* __restrict__ cnt,
                          const float* __restrict__ W1, const float* __restrict__ b1,
                          float* __restrict__ Gp)
{
    __shared__ float pr[128];
    int g = blockIdx.x, c = threadIdx.x;
    float inv = 1.f / fmaxf(cnt[g], 1.f);
    pr[c] = sums[g * 128 + c] * inv;
    __syncthreads();
    float acc = b1[c];
    for (int m = 0; m < 128; ++m) acc += pr[m] * W1[(272 + m) * 128 + c];
    Gp[g * 128 + c] = acc;
}

// ---------------------------------------------------------------------------
// final (fused, 2-round): per round, phase 1 computes a 16-row eaW tile per
// wave via single-acc MFMA into 4 KB of wave-private LDS (16 KB/block),
// phase 2 processes those 16 CSR slots (gather+add+relu+dot).
// ---------------------------------------------------------------------------
__global__ void __launch_bounds__(256)
edge_out_kernel(const _Float16* __restrict__ ABh, const float* __restrict__ Gp,
                const int4* __restrict__ ed4, const float* __restrict__ eac,
                const __bf16* __restrict__ pk, const float* __restrict__ W2,
                const float* __restrict__ b2, float* __restrict__ out)
{
    __shared__ _Float16 eawl[4][16 * 128];   // 16 KB total, 4 KB per wave
    int t = threadIdx.x, w = t >> 6, l = t & 63;
    int bid = xcd_swz(blockIdx.x, gridDim.x);
    int half = l >> 5, c = l & 31;
    int lr = l & 15, kq = l >> 4;
    float4 w2r = *(const float4*)(W2 + 4 * c);
    float bias2 = b2[0];
    int wbase = bid * 128 + w * 32;            // this wave's 32 CSR slots
    _Float16* myl = &eawl[w][0];
    #pragma unroll
    for (int rnd = 0; rnd < 2; ++rnd) {
        int rbase = wbase + rnd * 16;
        // ---- phase 1: eaW for rows [rbase, rbase+16) -> wave-private LDS ----
        {
            bf16x8 ah0, al0;
            if (kq < 2) {
                load_split(eac + (size_t)(rbase + lr) * 16 + kq * 8, true, ah0, al0);
            } else {
                #pragma unroll
                for (int j = 0; j < 8; ++j) { ah0[j] = (__bf16)0.f; al0[j] = (__bf16)0.f; }
            }
            #pragma unroll
            for (int ct = 0; ct < 8; ++ct) {
                f32x4 acc0 = {0.f, 0.f, 0.f, 0.f};
                const __bf16* blk = pk + (size_t)ct * 1024;
                bf16x8 bh = *(const bf16x8*)(blk + l * 8);
                bf16x8 bl = *(const bf16x8*)(blk + 512 + l * 8);
                acc0 = __builtin_amdgcn_mfma_f32_16x16x32_bf16(al0, bh, acc0, 0, 0, 0);
                acc0 = __builtin_amdgcn_mfma_f32_16x16x32_bf16(ah0, bl, acc0, 0, 0, 0);
                acc0 = __builtin_amdgcn_mfma_f32_16x16x32_bf16(ah0, bh, acc0, 0, 0, 0);
                int col = ct * 16 + lr;
                #pragma unroll
                for (int i = 0; i < 4; ++i)
                    myl[(kq * 4 + i) * 128 + col] = (_Float16)acc0[i];
            }
        }
        __syncthreads();
        // ---- phase 2: gather + add + relu + dot W2 over 16 slots ----
        for (int it = 0; it < 8; ++it) {
            int lrow = it * 2 + half;
            int idx = rbase + lrow;
            int4 q4 = ed4[idx];
            int e = q4.x, s = q4.y, d = q4.z, g = q4.w;
            h16x4 As = *(const h16x4*)(ABh + (size_t)s * 256 + 4 * c);
            h16x4 Bd = *(const h16x4*)(ABh + (size_t)d * 256 + 128 + 4 * c);
            h16x4 ew = *(const h16x4*)(myl + lrow * 128 + 4 * c);
            float4 Gg = *(const float4*)(Gp + g * 128 + 4 * c);
            float h0 = fmaxf((float)As[0] + (float)Bd[0] + Gg.x + (float)ew[0], 0.f);
            float h1 = fmaxf((float)As[1] + (float)Bd[1] + Gg.y + (float)ew[1], 0.f);
            float h2 = fmaxf((float)As[2] + (float)Bd[2] + Gg.z + (float)ew[2], 0.f);
            float h3 = fmaxf((float)As[3] + (float)Bd[3] + Gg.w + (float)ew[3], 0.f);
            float r = h0 * w2r.x + h1 * w2r.y + h2 * w2r.z + h3 * w2r.w;
            r += __shfl_xor(r, 1, 64);
            r += __shfl_xor(r, 2, 64);
            r += __shfl_xor(r, 4, 64);
            r += __shfl_xor(r, 8, 64);
            r += __shfl_xor(r, 16, 64);
            if (c == 0) out[e] = r + bias2;
        }
        __syncthreads();
    }
}

// ---------------------------------------------------------------------------
extern "C" void kernel_launch(void* const* d_in, const int* in_sizes, int n_in,
                              void* d_out, int out_size, void* d_ws, size_t ws_size,
                              hipStream_t stream)
{
    const float* x   = (const float*)d_in[0];
    const int* ei    = (const int*)d_in[1];
    const float* ea  = (const float*)d_in[2];
    const int* batch = (const int*)d_in[3];
    const float* Wq1 = (const float*)d_in[4];  const float* bq1 = (const float*)d_in[5];
    const float* Wk1 = (const float*)d_in[6];  const float* bk1 = (const float*)d_in[7];
    const float* Wv1 = (const float*)d_in[8];  const float* bv1 = (const float*)d_in[9];
    const float* We1 = (const float*)d_in[10];
    const float* Ws1 = (const float*)d_in[11]; const float* bs1 = (const float*)d_in[12];
    const float* Wq2 = (const float*)d_in[13]; const float* bq2 = (const float*)d_in[14];
    const float* Wk2 = (const float*)d_in[15]; const float* bk2 = (const float*)d_in[16];
    const float* Wv2 = (const float*)d_in[17]; const float* bv2 = (const float*)d_in[18];
    const float* We2 = (const float*)d_in[19];
    const float* Ws2 = (const float*)d_in[20]; const float* bs2 = (const float*)d_in[21];
    const float* W1  = (const float*)d_in[22]; const float* b1  = (const float*)d_in[23];
    const float* W2  = (const float*)d_in[24]; const float* b2  = (const float*)d_in[25];

    const int* src = ei;
    const int* dst = ei + NE;

    float* ws = (float*)d_ws;
    size_t off = 0;
    float* REG  = ws + off; off += (size_t)NN * 640;  // QSPh -> later ABh
    float* h1   = ws + off; off += (size_t)NN * 128;
    float* h2   = ws + off; off += (size_t)NN * 128;
    float* eac  = ws + off; off += (size_t)NE * 16;
    _Float16* KVh = (_Float16*)(ws + off); off += (size_t)NN * 128;  // N x 256 half
    float* sums = ws + off; off += NG * 128;
    float* cntf = ws + off; off += NG;
    float* Gp   = ws + off; off += NG * 128;
    float* Wp1  = ws + off; off += 64 * 128;
    float* Wp2  = ws + off; off += 128 * 16;
    float* bcat1 = ws + off; off += 640;
    float* bcat2 = ws + off; off += 528;
    __bf16* pk  = (__bf16*)(ws + off); off += 284 * 1024 / 2;  // 284 blocks x 1024 bf16
    int* cnt_arr   = (int*)(ws + off); off += NN;
    int* row_start = (int*)(ws + off); off += NN + 1;
    int* cursor    = (int*)(ws + off); off += NN;
    int* se        = (int*)(ws + off); off += NE;
    int* bsum      = (int*)(ws + off); off += 64;
    off = (off + 3) & ~(size_t)3;                      // 16B align for int4
    int4* ed4      = (int4*)(ws + off); off += (size_t)NE * 4;
    // aliases inside REG:
    _Float16* QSPh = (_Float16*)REG;                   // L1 stride 384 / L2 stride 272
    _Float16* ABh  = (_Float16*)REG;                   // after agg2

    hipMemsetAsync(cnt_arr, 0, NN * sizeof(int), stream);
    hipMemsetAsync(sums, 0, (NG * 128 + NG) * sizeof(float), stream);

    prep_kernel<<<45, 256, 0, stream>>>(Wq1, bq1, bk1, bv1, bs1, We1,
                                        Wq2, bq2, bk2, bv2, bs2, We2,
                                        Wp1, Wp2, bcat1, bcat2);
    pack_kernel<<<284, 256, 0, stream>>>(Wq1, Wk1, Wv1, Ws1, Wp1,
                                         Wq2, Wk2, Wv2, Ws2, Wp2, W1, pk);
    count_kernel<<<(NE + 255) / 256, 256, 0, stream>>>(dst, cnt_arr);
    scanA_kernel<<<SCAN_B, 1024, 0, stream>>>(cnt_arr, row_start, bsum);
    scanC_kernel<<<SCAN_B, 1024, 0, stream>>>(row_start, bsum, cursor);
    scatter_kernel<<<(NE + 255) / 256, 256, 0, stream>>>(src, dst, batch, ea, cursor,
                                                         ed4, se, eac);

    dim3 g1((NN + 127) / 128, 5);
    mfma_gemm_kernel<64, 40, 5, true, 128, 384, 384><<<g1, 256, 0, stream>>>(
        x, pk, bcat1, QSPh, KVh);
    agg1_kernel<<<(NN + 3) / 4, 256, 0, stream>>>(QSPh, KVh, row_start, se, eac, We1, h1);
    dim3 g2((NN + 127) / 128, 6);
    mfma_gemm_kernel<128, 33, 6, true, 128, 384, 272><<<g2, 256, 0, stream>>>(
        h1, pk + (size_t)80 * 1024, bcat2, QSPh, KVh);
    agg2_kernel<<<(NN + 3) / 4, 256, 0, stream>>>(QSPh, KVh, row_start, se, eac, We2, h2);
    pool_kernel<<<(NN + 63) / 64, 256, 0, stream>>>(h2, batch, sums, cntf);
    gp_kernel<<<NG, 128, 0, stream>>>(sums, cntf, W1, b1, Gp);
    dim3 g3((NN + 127) / 128, 2);
    mfma_gemm_kernel<128, 16, 2, false, 0, 256, 0><<<g3, 256, 0, stream>>>(
        h2, pk + (size_t)212 * 1024, nullptr, nullptr, ABh);
    edge_out_kernel<<<NE / 128, 256, 0, stream>>>(ABh, Gp, ed4, eac,
                                                  pk + (size_t)276 * 1024,
                                                  W2, b2, (float*)d_out);
}

// Round 20
// 418.947 us; speedup vs baseline: 1.0962x; 1.0962x over previous
//
#include <hip/hip_runtime.h>
#include <math.h>

#define NN 50000
#define NE 400000
#define NG 128
#define SCAN_B 49   // ceil(NN/1024)

typedef __bf16 bf16x8 __attribute__((ext_vector_type(8)));
typedef float f32x4 __attribute__((ext_vector_type(4)));
typedef _Float16 h16x4 __attribute__((ext_vector_type(4)));

// bijective XCD-chunked swizzle (m204): each XCD gets a contiguous chunk
__device__ __forceinline__ int xcd_swz(int bid, int nwg)
{
    int q = nwg >> 3, r = nwg & 7;
    int xcd = bid & 7, off = bid >> 3;
    return (xcd < r ? xcd * (q + 1) : r * (q + 1) + (xcd - r) * q) + off;
}

// ---------------------------------------------------------------------------
// prep: fused weights Wp1[64,128], Wp2[128,16]; concatenated biases
// ---------------------------------------------------------------------------
__global__ void prep_kernel(const float* __restrict__ Wq1, const float* __restrict__ bq1,
                            const float* __restrict__ bk1, const float* __restrict__ bv1,
                            const float* __restrict__ bs1, const float* __restrict__ We1,
                            const float* __restrict__ Wq2, const float* __restrict__ bq2,
                            const float* __restrict__ bk2, const float* __restrict__ bv2,
                            const float* __restrict__ bs2, const float* __restrict__ We2,
                            float* __restrict__ Wp1, float* __restrict__ Wp2,
                            float* __restrict__ bcat1, float* __restrict__ bcat2)
{
    int idx = blockIdx.x * blockDim.x + threadIdx.x;
    if (idx < 8192) {                       // Wp1[64,128]
        int m = idx >> 7, c = idx & 127;
        int h = c >> 4, d = c & 15;
        float s = 0.f;
        #pragma unroll
        for (int j = 0; j < 16; ++j)
            s += Wq1[m * 128 + h * 16 + j] * We1[d * 128 + h * 16 + j];
        Wp1[idx] = s;
    } else if (idx < 8320) {                // bp1 -> bcat1[512..640)
        int c = idx - 8192;
        int h = c >> 4, d = c & 15;
        float s = 0.f;
        #pragma unroll
        for (int j = 0; j < 16; ++j)
            s += bq1[h * 16 + j] * We1[d * 128 + h * 16 + j];
        bcat1[512 + c] = s;
    } else if (idx < 10368) {               // Wp2[128,16]
        int i = idx - 8320;
        int m = i >> 4, d = i & 15;
        float s = 0.f;
        for (int j = 0; j < 128; ++j)
            s += Wq2[m * 128 + j] * We2[d * 128 + j];
        Wp2[m * 16 + d] = s;
    } else if (idx < 10384) {               // bp2 -> bcat2[512..528)
        int d = idx - 10368;
        float s = 0.f;
        for (int j = 0; j < 128; ++j)
            s += bq2[j] * We2[d * 128 + j];
        bcat2[512 + d] = s;
    } else if (idx < 10896) {               // bcat1[0..512)
        int i = idx - 10384;
        int seg = i >> 7, c = i & 127;
        const float* b = (seg == 0) ? bq1 : (seg == 1) ? bk1 : (seg == 2) ? bv1 : bs1;
        bcat1[i] = b[c];
    } else if (idx < 11408) {               // bcat2[0..512)
        int i = idx - 10896;
        int seg = i >> 7, c = i & 127;
        const float* b = (seg == 0) ? bq2 : (seg == 1) ? bk2 : (seg == 2) ? bv2 : bs2;
        bcat2[i] = b[c];
    }
}

// ---------------------------------------------------------------------------
// pack: MFMA fragment-ready hi/lo bf16 weight blocks.
//   mat0: gemm1 Wcat[64,640]   blocks 0..79
//   mat1: gemm2 Wcat[128,528]  blocks 80..211
//   mat2: gemm3 Wcat[128,256]  blocks 212..275
//   mat3: W1c[16->32pad,128]   blocks 276..283 (for fused eaW in edge_out)
// ---------------------------------------------------------------------------
__global__ void pack_kernel(const float* __restrict__ Wq1, const float* __restrict__ Wk1,
                            const float* __restrict__ Wv1, const float* __restrict__ Ws1,
                            const float* __restrict__ Wp1,
                            const float* __restrict__ Wq2, const float* __restrict__ Wk2,
                            const float* __restrict__ Wv2, const float* __restrict__ Ws2,
                            const float* __restrict__ Wp2,
                            const float* __restrict__ W1,
                            __bf16* __restrict__ pk)
{
    int b = blockIdx.x;
    int mat, kt, ct;
    if (b < 80)       { mat = 0; kt = b / 40;        ct = b % 40; }
    else if (b < 212) { mat = 1; kt = (b - 80) / 33; ct = (b - 80) % 33; }
    else if (b < 276) { mat = 2; kt = (b - 212) / 16; ct = (b - 212) % 16; }
    else              { mat = 3; kt = 0;             ct = b - 276; }
    __bf16* blkp = pk + (size_t)b * 1024;
    for (int item = threadIdx.x; item < 512; item += 256) {
        int lane = item >> 3, j = item & 7;
        int k = kt * 32 + (lane >> 4) * 8 + j;
        int col = ct * 16 + (lane & 15);
        float v;
        if (mat == 0) {
            int seg = col >> 7, cc = col & 127;
            const float* W = (seg == 0) ? Wq1 : (seg == 1) ? Wk1 : (seg == 2) ? Wv1
                             : (seg == 3) ? Ws1 : Wp1;
            v = W[k * 128 + cc];
        } else if (mat == 1) {
            if (col < 512) {
                int seg = col >> 7, cc = col & 127;
                const float* W = (seg == 0) ? Wq2 : (seg == 1) ? Wk2 : (seg == 2) ? Wv2 : Ws2;
                v = W[k * 128 + cc];
            } else {
                v = Wp2[k * 16 + (col - 512)];
            }
        } else if (mat == 2) {
            v = (col < 128) ? W1[k * 128 + col] : W1[(size_t)(128 + k) * 128 + (col - 128)];
        } else {
            v = (k < 16) ? W1[(size_t)(256 + k) * 128 + col] : 0.f;
        }
        __bf16 h = (__bf16)v;
        __bf16 lo = (__bf16)(v - (float)h);
        blkp[lane * 8 + j] = h;
        blkp[512 + lane * 8 + j] = lo;
    }
}

// ---------------------------------------------------------------------------
// CSR build by dst — count, 2-dispatch parallel scan, scatter(+ea copy fused)
// ---------------------------------------------------------------------------
__global__ void count_kernel(const int* __restrict__ dst, int* __restrict__ counts)
{
    int e = blockIdx.x * blockDim.x + threadIdx.x;
    if (e < NE) atomicAdd(&counts[dst[e]], 1);
}

__global__ void scanA_kernel(const int* __restrict__ counts,
                             int* __restrict__ row_start, int* __restrict__ bsum)
{
    __shared__ int lds[1024];
    int t = threadIdx.x, b = blockIdx.x;
    int i = b * 1024 + t;
    int v = (i < NN) ? counts[i] : 0;
    lds[t] = v;
    __syncthreads();
    for (int off = 1; off < 1024; off <<= 1) {
        int u = (t >= off) ? lds[t - off] : 0;
        __syncthreads();
        lds[t] += u;
        __syncthreads();
    }
    if (i < NN) row_start[i] = lds[t] - v;     // block-local exclusive
    if (t == 1023) bsum[b] = lds[1023];
}

// scanC: each block redundantly scans bsum (49 values) in wave 0, then adds
// its own exclusive block offset (merges old scanB into scanC).
__global__ void scanC_kernel(int* __restrict__ row_start, const int* __restrict__ bsum,
                             int* __restrict__ cursor)
{
    __shared__ int boff_s;
    int t = threadIdx.x;
    if (t < 64) {
        int orig = (t < SCAN_B) ? bsum[t] : 0;
        int v = orig;
        #pragma unroll
        for (int off = 1; off < 64; off <<= 1) {
            int u = __shfl_up(v, off, 64);
            if (t >= off) v += u;
        }
        if (t == blockIdx.x) boff_s = v - orig;
    }
    __syncthreads();
    int i = blockIdx.x * 1024 + t;
    if (i < NN) {
        int rs = row_start[i] + boff_s;
        row_start[i] = rs;
        cursor[i] = rs;
    }
    if (i == 0) row_start[NN] = NE;
}

// scatter: CSR placement + ed4/se side arrays + eac copy (ea read is
// sequential in e -> coalesced; eac write is scattered full 64B lines)
__global__ void scatter_kernel(const int* __restrict__ src, const int* __restrict__ dst,
                               const int* __restrict__ batch, const float* __restrict__ ea,
                               int* __restrict__ cursor, int4* __restrict__ ed4,
                               int* __restrict__ se, float* __restrict__ eac)
{
    int e = blockIdx.x * blockDim.x + threadIdx.x;
    if (e < NE) {
        int d = dst[e];
        int s = src[e];
        int p = atomicAdd(&cursor[d], 1);
        ed4[p] = make_int4(e, s, d, batch[s]);
        se[p] = s;
        const float* ap = ea + (size_t)e * 16;
        float4 a0 = *(const float4*)ap;
        float4 a1 = *(const float4*)(ap + 4);
        float4 a2 = *(const float4*)(ap + 8);
        float4 a3 = *(const float4*)(ap + 12);
        float* ep = eac + (size_t)p * 16;
        *(float4*)ep = a0;
        *(float4*)(ep + 4) = a1;
        *(float4*)(ep + 8) = a2;
        *(float4*)(ep + 12) = a3;
    }
}

// ---------------------------------------------------------------------------
// MFMA GEMM, split-bf16 3-term. All outputs fp16:
//   cols [CLO,CHI) -> auxh (width CHI-CLO); others -> outh (width OW, remapped)
// Column tiles split across blockIdx.y (NCG groups) for occupancy.
// ---------------------------------------------------------------------------
__device__ __forceinline__ void load_split(const float* ap, bool ok,
                                           bf16x8& hv, bf16x8& lv)
{
    float av[8];
    if (ok) {
        float4 f0 = *(const float4*)ap;
        float4 f1 = *(const float4*)(ap + 4);
        av[0] = f0.x; av[1] = f0.y; av[2] = f0.z; av[3] = f0.w;
        av[4] = f1.x; av[5] = f1.y; av[6] = f1.z; av[7] = f1.w;
    } else {
        #pragma unroll
        for (int j = 0; j < 8; ++j) av[j] = 0.f;
    }
    #pragma unroll
    for (int j = 0; j < 8; ++j) {
        __bf16 h = (__bf16)av[j];
        hv[j] = h;
        lv[j] = (__bf16)(av[j] - (float)h);
    }
}

template<int KD, int NCT, int NCG, bool BIAS, int CLO, int CHI, int OW>
__global__ void mfma_gemm_kernel(const float* __restrict__ A, const __bf16* __restrict__ pk,
                                 const float* __restrict__ bias,
                                 _Float16* __restrict__ outh,
                                 _Float16* __restrict__ auxh)
{
    constexpr int NKT = KD / 32;
    constexpr int AUXW = CHI - CLO;
    constexpr int CPG = (NCT + NCG - 1) / NCG;
    int cg = blockIdx.y;
    int ct0 = cg * CPG;
    int ct1 = (ct0 + CPG < NCT) ? ct0 + CPG : NCT;
    int t = threadIdx.x, w = t >> 6, l = t & 63;
    int rbase = blockIdx.x * 128 + w * 32;
    int lr = l & 15, kq = l >> 4;
    int r0 = rbase + lr, r1 = rbase + 16 + lr;
    bool ok0 = r0 < NN, ok1 = r1 < NN;
    bf16x8 ah0[NKT], al0[NKT], ah1[NKT], al1[NKT];
    #pragma unroll
    for (int kt = 0; kt < NKT; ++kt) {
        load_split(A + (size_t)r0 * KD + kt * 32 + kq * 8, ok0, ah0[kt], al0[kt]);
        load_split(A + (size_t)r1 * KD + kt * 32 + kq * 8, ok1, ah1[kt], al1[kt]);
    }
    for (int ct = ct0; ct < ct1; ++ct) {
        float b = BIAS ? bias[ct * 16 + lr] : 0.f;
        f32x4 acc0 = {b, b, b, b};
        f32x4 acc1 = {b, b, b, b};
        const __bf16* blk = pk + (size_t)ct * 1024;
        #pragma unroll
        for (int kt = 0; kt < NKT; ++kt) {
            bf16x8 bh = *(const bf16x8*)(blk + (size_t)kt * NCT * 1024 + l * 8);
            bf16x8 bl = *(const bf16x8*)(blk + (size_t)kt * NCT * 1024 + 512 + l * 8);
            acc0 = __builtin_amdgcn_mfma_f32_16x16x32_bf16(al0[kt], bh, acc0, 0, 0, 0);
            acc1 = __builtin_amdgcn_mfma_f32_16x16x32_bf16(al1[kt], bh, acc1, 0, 0, 0);
            acc0 = __builtin_amdgcn_mfma_f32_16x16x32_bf16(ah0[kt], bl, acc0, 0, 0, 0);
            acc1 = __builtin_amdgcn_mfma_f32_16x16x32_bf16(ah1[kt], bl, acc1, 0, 0, 0);
            acc0 = __builtin_amdgcn_mfma_f32_16x16x32_bf16(ah0[kt], bh, acc0, 0, 0, 0);
            acc1 = __builtin_amdgcn_mfma_f32_16x16x32_bf16(ah1[kt], bh, acc1, 0, 0, 0);
        }
        int col = ct * 16 + lr;
        bool inAux = (col >= CLO) && (col < CHI);
        int mcol = (col < CLO) ? col : col - AUXW;
        #pragma unroll
        for (int i = 0; i < 4; ++i) {
            int ra = rbase + kq * 4 + i;
            int rb = ra + 16;
            if (ra < NN) {
                if (inAux) auxh[(size_t)ra * AUXW + (col - CLO)] = (_Float16)acc0[i];
                else if constexpr (OW > 0) outh[(size_t)ra * OW + mcol] = (_Float16)acc0[i];
            }
            if (rb < NN) {
                if (inAux) auxh[(size_t)rb * AUXW + (col - CLO)] = (_Float16)acc1[i];
                else if constexpr (OW > 0) outh[(size_t)rb * OW + mcol] = (_Float16)acc1[i];
            }
        }
    }
}

// ---------------------------------------------------------------------------
// agg1: wave per node, half-wave per edge, 2-deep edge unroll.
// Lane c owns dims [4c,4c+4); head h = c>>2. QSPh [Q|S|P] fp16 stride 384.
// ---------------------------------------------------------------------------
__global__ void agg1_kernel(const _Float16* __restrict__ QSPh, const _Float16* __restrict__ KVh,
                            const int* __restrict__ row_start,
                            const int* __restrict__ se, const float* __restrict__ eac,
                            const float* __restrict__ We1, float* __restrict__ h1)
{
    __shared__ float we[16 * 128];
    int t = threadIdx.x;
    for (int i = t; i < 2048; i += 256) we[i] = We1[i];
    __syncthreads();
    int bid = xcd_swz(blockIdx.x, gridDim.x);
    int wv = t >> 6, l = t & 63;
    int n = bid * 4 + wv;
    if (n >= NN) return;
    int half = l >> 5, c = l & 31;
    const _Float16* qb = QSPh + (size_t)n * 384;
    h16x4 qh = *(const h16x4*)(qb + 4 * c);
    h16x4 Ph = *(const h16x4*)(qb + 256 + 4 * c);
    float q0 = qh[0], q1 = qh[1], q2 = qh[2], q3 = qh[3];
    float P0 = Ph[0], P1 = Ph[1], P2 = Ph[2], P3 = Ph[3];
    float av0 = 0.f, av1 = 0.f, av2 = 0.f, av3 = 0.f;
    float ae0 = 0.f, ae1 = 0.f, ae2 = 0.f, ae3 = 0.f, denom = 0.f;
    int e0 = row_start[n], e1 = row_start[n + 1];
    int idx = e0 + half;
    int eoff = (c & 3) * 4;
    for (; idx + 2 < e1; idx += 4) {
        int sA = se[idx], sB = se[idx + 2];
        const _Float16* ka = KVh + (size_t)sA * 256;
        const _Float16* kbp = KVh + (size_t)sB * 256;
        h16x4 kA = *(const h16x4*)(ka + 4 * c);
        h16x4 vA = *(const h16x4*)(ka + 128 + 4 * c);
        h16x4 kB = *(const h16x4*)(kbp + 4 * c);
        h16x4 vB = *(const h16x4*)(kbp + 128 + 4 * c);
        float4 eA = *(const float4*)(eac + (size_t)idx * 16 + eoff);
        float4 eB = *(const float4*)(eac + (size_t)(idx + 2) * 16 + eoff);
        float pa = q0 * (float)kA[0] + q1 * (float)kA[1]
                 + q2 * (float)kA[2] + q3 * (float)kA[3]
                 + P0 * eA.x + P1 * eA.y + P2 * eA.z + P3 * eA.w;
        float pb = q0 * (float)kB[0] + q1 * (float)kB[1]
                 + q2 * (float)kB[2] + q3 * (float)kB[3]
                 + P0 * eB.x + P1 * eB.y + P2 * eB.z + P3 * eB.w;
        pa += __shfl_xor(pa, 1, 64); pb += __shfl_xor(pb, 1, 64);
        pa += __shfl_xor(pa, 2, 64); pb += __shfl_xor(pb, 2, 64);
        float wA = __expf(pa * 0.25f);
        float wB = __expf(pb * 0.25f);
        denom += wA + wB;
        av0 += wA * (float)vA[0] + wB * (float)vB[0];
        av1 += wA * (float)vA[1] + wB * (float)vB[1];
        av2 += wA * (float)vA[2] + wB * (float)vB[2];
        av3 += wA * (float)vA[3] + wB * (float)vB[3];
        ae0 += wA * eA.x + wB * eB.x;
        ae1 += wA * eA.y + wB * eB.y;
        ae2 += wA * eA.z + wB * eB.z;
        ae3 += wA * eA.w + wB * eB.w;
    }
    if (idx < e1) {
        int s = se[idx];
        const _Float16* kb = KVh + (size_t)s * 256;
        h16x4 k4 = *(const h16x4*)(kb + 4 * c);
        h16x4 v4 = *(const h16x4*)(kb + 128 + 4 * c);
        float4 ea4 = *(const float4*)(eac + (size_t)idx * 16 + eoff);
        float part = q0 * (float)k4[0] + q1 * (float)k4[1]
                   + q2 * (float)k4[2] + q3 * (float)k4[3]
                   + P0 * ea4.x + P1 * ea4.y + P2 * ea4.z + P3 * ea4.w;
        part += __shfl_xor(part, 1, 64);
        part += __shfl_xor(part, 2, 64);
        float w = __expf(part * 0.25f);
        denom += w;
        av0 += w * (float)v4[0]; av1 += w * (float)v4[1];
        av2 += w * (float)v4[2]; av3 += w * (float)v4[3];
        ae0 += w * ea4.x; ae1 += w * ea4.y; ae2 += w * ea4.z; ae3 += w * ea4.w;
    }
    denom += __shfl_xor(denom, 32, 64);
    av0 += __shfl_xor(av0, 32, 64); av1 += __shfl_xor(av1, 32, 64);
    av2 += __shfl_xor(av2, 32, 64); av3 += __shfl_xor(av3, 32, 64);
    ae0 += __shfl_xor(ae0, 32, 64); ae1 += __shfl_xor(ae1, 32, 64);
    ae2 += __shfl_xor(ae2, 32, 64); ae3 += __shfl_xor(ae3, 32, 64);
    float inv = (denom > 0.f) ? 1.f / denom : 0.f;
    float es0 = 0.f, es1 = 0.f, es2 = 0.f, es3 = 0.f;
    int gb = l & 60;                               // 4-lane group base (same half)
    #pragma unroll
    for (int dd = 0; dd < 4; ++dd) {
        int srcl = gb + dd;
        float a0 = __shfl(ae0, srcl, 64);
        float a1 = __shfl(ae1, srcl, 64);
        float a2 = __shfl(ae2, srcl, 64);
        float a3 = __shfl(ae3, srcl, 64);
        int d0 = dd * 4;
        float4 w0 = *(const float4*)&we[(d0 + 0) * 128 + 4 * c];
        float4 w1 = *(const float4*)&we[(d0 + 1) * 128 + 4 * c];
        float4 w2 = *(const float4*)&we[(d0 + 2) * 128 + 4 * c];
        float4 w3 = *(const float4*)&we[(d0 + 3) * 128 + 4 * c];
        es0 += a0 * w0.x + a1 * w1.x + a2 * w2.x + a3 * w3.x;
        es1 += a0 * w0.y + a1 * w1.y + a2 * w2.y + a3 * w3.y;
        es2 += a0 * w0.z + a1 * w1.z + a2 * w2.z + a3 * w3.z;
        es3 += a0 * w0.w + a1 * w1.w + a2 * w2.w + a3 * w3.w;
    }
    if (half == 0) {
        h16x4 s4 = *(const h16x4*)(qb + 128 + 4 * c);
        float o0 = (av0 + es0) * inv + (float)s4[0];
        float o1 = (av1 + es1) * inv + (float)s4[1];
        float o2 = (av2 + es2) * inv + (float)s4[2];
        float o3 = (av3 + es3) * inv + (float)s4[3];
        o0 = (o0 > 0.f) ? o0 : 0.01f * o0;
        o1 = (o1 > 0.f) ? o1 : 0.01f * o1;
        o2 = (o2 > 0.f) ? o2 : 0.01f * o2;
        o3 = (o3 > 0.f) ? o3 : 0.01f * o3;
        *(float4*)(h1 + (size_t)n * 128 + 4 * c) = make_float4(o0, o1, o2, o3);
    }
}

// ---------------------------------------------------------------------------
// agg2: wave per node, half-wave per edge, 2-deep edge unroll.
// Lane c owns dims [4c,4c+4). QSPh [Q|S|P2] fp16 stride 272.
// ---------------------------------------------------------------------------
__global__ void agg2_kernel(const _Float16* __restrict__ QSPh, const _Float16* __restrict__ KVh,
                            const int* __restrict__ row_start,
                            const int* __restrict__ se, const float* __restrict__ eac,
                            const float* __restrict__ We2, float* __restrict__ h2)
{
    int bid = xcd_swz(blockIdx.x, gridDim.x);
    int t = threadIdx.x;
    int wv = t >> 6, l = t & 63;
    int n = bid * 4 + wv;
    if (n >= NN) return;
    int half = l >> 5, c = l & 31;
    const _Float16* qb = QSPh + (size_t)n * 272;
    h16x4 qh = *(const h16x4*)(qb + 4 * c);
    float q0 = qh[0], q1 = qh[1], q2 = qh[2], q3 = qh[3];
    float p0 = 0.f, p1 = 0.f, p2 = 0.f, p3 = 0.f;
    if (c < 4) {
        h16x4 ph = *(const h16x4*)(qb + 256 + 4 * c);
        p0 = ph[0]; p1 = ph[1]; p2 = ph[2]; p3 = ph[3];
    }
    float av0 = 0.f, av1 = 0.f, av2 = 0.f, av3 = 0.f;
    float ae0 = 0.f, ae1 = 0.f, ae2 = 0.f, ae3 = 0.f, denom = 0.f;
    int e0 = row_start[n], e1 = row_start[n + 1];
    int idx = e0 + half;
    for (; idx + 2 < e1; idx += 4) {
        int sA = se[idx], sB = se[idx + 2];
        const _Float16* ka = KVh + (size_t)sA * 256;
        const _Float16* kbp = KVh + (size_t)sB * 256;
        h16x4 kA = *(const h16x4*)(ka + 4 * c);
        h16x4 vA = *(const h16x4*)(ka + 128 + 4 * c);
        h16x4 kB = *(const h16x4*)(kbp + 4 * c);
        h16x4 vB = *(const h16x4*)(kbp + 128 + 4 * c);
        float4 eA = (c < 4) ? *(const float4*)(eac + (size_t)idx * 16 + 4 * c)
                            : make_float4(0.f, 0.f, 0.f, 0.f);
        float4 eB = (c < 4) ? *(const float4*)(eac + (size_t)(idx + 2) * 16 + 4 * c)
                            : make_float4(0.f, 0.f, 0.f, 0.f);
        float pa = q0 * (float)kA[0] + q1 * (float)kA[1]
                 + q2 * (float)kA[2] + q3 * (float)kA[3]
                 + p0 * eA.x + p1 * eA.y + p2 * eA.z + p3 * eA.w;
        float pb = q0 * (float)kB[0] + q1 * (float)kB[1]
                 + q2 * (float)kB[2] + q3 * (float)kB[3]
                 + p0 * eB.x + p1 * eB.y + p2 * eB.z + p3 * eB.w;
        pa += __shfl_xor(pa, 1, 64); pb += __shfl_xor(pb, 1, 64);
        pa += __shfl_xor(pa, 2, 64); pb += __shfl_xor(pb, 2, 64);
        pa += __shfl_xor(pa, 4, 64); pb += __shfl_xor(pb, 4, 64);
        pa += __shfl_xor(pa, 8, 64); pb += __shfl_xor(pb, 8, 64);
        pa += __shfl_xor(pa, 16, 64); pb += __shfl_xor(pb, 16, 64);
        float wA = __expf(pa * 0.08838834764831845f);
        float wB = __expf(pb * 0.08838834764831845f);
        denom += wA + wB;
        av0 += wA * (float)vA[0] + wB * (float)vB[0];
        av1 += wA * (float)vA[1] + wB * (float)vB[1];
        av2 += wA * (float)vA[2] + wB * (float)vB[2];
        av3 += wA * (float)vA[3] + wB * (float)vB[3];
        ae0 += wA * eA.x + wB * eB.x;
        ae1 += wA * eA.y + wB * eB.y;
        ae2 += wA * eA.z + wB * eB.z;
        ae3 += wA * eA.w + wB * eB.w;
    }
    if (idx < e1) {
        int s = se[idx];
        const _Float16* kb = KVh + (size_t)s * 256;
        h16x4 k4 = *(const h16x4*)(kb + 4 * c);
        h16x4 v4 = *(const h16x4*)(kb + 128 + 4 * c);
        float4 ea4 = (c < 4) ? *(const float4*)(eac + (size_t)idx * 16 + 4 * c)
                             : make_float4(0.f, 0.f, 0.f, 0.f);
        float part = q0 * (float)k4[0] + q1 * (float)k4[1]
                   + q2 * (float)k4[2] + q3 * (float)k4[3]
                   + p0 * ea4.x + p1 * ea4.y + p2 * ea4.z + p3 * ea4.w;
        part += __shfl_xor(part, 1, 64);
        part += __shfl_xor(part, 2, 64);
        part += __shfl_xor(part, 4, 64);
        part += __shfl_xor(part, 8, 64);
        part += __shfl_xor(part, 16, 64);
        float w = __expf(part * 0.08838834764831845f);
        denom += w;
        av0 += w * (float)v4[0]; av1 += w * (float)v4[1];
        av2 += w * (float)v4[2]; av3 += w * (float)v4[3];
        ae0 += w * ea4.x; ae1 += w * ea4.y; ae2 += w * ea4.z; ae3 += w * ea4.w;
    }
    denom += __shfl_xor(denom, 32, 64);
    av0 += __shfl_xor(av0, 32, 64); av1 += __shfl_xor(av1, 32, 64);
    av2 += __shfl_xor(av2, 32, 64); av3 += __shfl_xor(av3, 32, 64);
    ae0 += __shfl_xor(ae0, 32, 64); ae1 += __shfl_xor(ae1, 32, 64);
    ae2 += __shfl_xor(ae2, 32, 64); ae3 += __shfl_xor(ae3, 32, 64);
    float inv = (denom > 0.f) ? 1.f / denom : 0.f;
    float t0 = 0.f, t1 = 0.f, t2 = 0.f, t3 = 0.f;
    #pragma unroll
    for (int dd = 0; dd < 4; ++dd) {
        float a0 = __shfl(ae0, dd, 64);
        float a1 = __shfl(ae1, dd, 64);
        float a2 = __shfl(ae2, dd, 64);
        float a3 = __shfl(ae3, dd, 64);
        int d0 = dd * 4;
        float4 w0 = *(const float4*)(We2 + (size_t)(d0 + 0) * 128 + 4 * c);
        float4 w1 = *(const float4*)(We2 + (size_t)(d0 + 1) * 128 + 4 * c);
        float4 w2 = *(const float4*)(We2 + (size_t)(d0 + 2) * 128 + 4 * c);
        float4 w3 = *(const float4*)(We2 + (size_t)(d0 + 3) * 128 + 4 * c);
        t0 += a0 * w0.x + a1 * w1.x + a2 * w2.x + a3 * w3.x;
        t1 += a0 * w0.y + a1 * w1.y + a2 * w2.y + a3 * w3.y;
        t2 += a0 * w0.z + a1 * w1.z + a2 * w2.z + a3 * w3.z;
        t3 += a0 * w0.w + a1 * w1.w + a2 * w2.w + a3 * w3.w;
    }
    if (half == 0) {
        h16x4 s4 = *(const h16x4*)(qb + 128 + 4 * c);
        float o0 = (av0 + t0) * inv + (float)s4[0];
        float o1 = (av1 + t1) * inv + (float)s4[1];
        float o2 = (av2 + t2) * inv + (float)s4[2];
        float o3 = (av3 + t3) * inv + (float)s4[3];
        *(float4*)(h2 + (size_t)n * 128 + 4 * c) = make_float4(o0, o1, o2, o3);
    }
}

// ---------------------------------------------------------------------------
// pooling: sorted batch -> register-accumulated flushes
// ---------------------------------------------------------------------------
__global__ void pool_kernel(const float* __restrict__ h2, const int* __restrict__ batch,
                            float* __restrict__ sums, float* __restrict__ cnt)
{
    int t = threadIdx.x;
    int c = t & 127, half = t >> 7;
    int n0 = blockIdx.x * 64;
    float acc = 0.f, cacc = 0.f;
    int curg = -1;
    for (int r = half; r < 64; r += 2) {
        int n = n0 + r;
        if (n >= NN) break;
        int g = batch[n];
        if (g != curg) {
            if (curg >= 0) {
                atomicAdd(&sums[curg * 128 + c], acc);
                if (c == 0) atomicAdd(&cnt[curg], cacc);
            }
            curg = g; acc = 0.f; cacc = 0.f;
        }
        acc += h2[(size_t)n * 128 + c];
        cacc += 1.f;
    }
    if (curg >= 0) {
        atomicAdd(&sums[curg * 128 + c], acc);
        if (c == 0) atomicAdd(&cnt[curg], cacc);
    }
}

// Gp[g,c] = b1[c] + sum_m pool[g,m] * W1[272+m, c]
__global__ void gp_kernel(const float* __restrict__ sums, const float* __restrict__ cnt,
                          const float* __restrict__ W1, const float* __restrict__ b1,
                          float* __restrict__ Gp)
{
    __shared__ float pr[128];
    int g = blockIdx.x, c = threadIdx.x;
    float inv = 1.f / fmaxf(cnt[g], 1.f);
    pr[c] = sums[g * 128 + c] * inv;
    __syncthreads();
    float acc = b1[c];
    for (int m = 0; m < 128; ++m) acc += pr[m] * W1[(272 + m) * 128 + c];
    Gp[g * 128 + c] = acc;
}

// ---------------------------------------------------------------------------
// final (fused, 2-round): per round, phase 1 computes a 16-row eaW tile per
// wave via single-acc MFMA into 4 KB of wave-private LDS (16 KB/block),
// phase 2 processes those 16 CSR slots (gather+add+relu+dot).
// ---------------------------------------------------------------------------
__global__ void __launch_bounds__(256)
edge_out_kernel(const _Float16* __restrict__ ABh, const float* __restrict__ Gp,
                const int4* __restrict__ ed4, const float* __restrict__ eac,
                const __bf16* __restrict__ pk, const float* __restrict__ W2,
                const float* __restrict__ b2, float* __restrict__ out)
{
    __shared__ _Float16 eawl[4][16 * 128];   // 16 KB total, 4 KB per wave
    int t = threadIdx.x, w = t >> 6, l = t & 63;
    int bid = xcd_swz(blockIdx.x, gridDim.x);
    int half = l >> 5, c = l & 31;
    int lr = l & 15, kq = l >> 4;
    float4 w2r = *(const float4*)(W2 + 4 * c);
    float bias2 = b2[0];
    int wbase = bid * 128 + w * 32;            // this wave's 32 CSR slots
    _Float16* myl = &eawl[w][0];
    #pragma unroll
    for (int rnd = 0; rnd < 2; ++rnd) {
        int rbase = wbase + rnd * 16;
        // ---- phase 1: eaW for rows [rbase, rbase+16) -> wave-private LDS ----
        {
            bf16x8 ah0, al0;
            if (kq < 2) {
                load_split(eac + (size_t)(rbase + lr) * 16 + kq * 8, true, ah0, al0);
            } else {
                #pragma unroll
                for (int j = 0; j < 8; ++j) { ah0[j] = (__bf16)0.f; al0[j] = (__bf16)0.f; }
            }
            #pragma unroll
            for (int ct = 0; ct < 8; ++ct) {
                f32x4 acc0 = {0.f, 0.f, 0.f, 0.f};
                const __bf16* blk = pk + (size_t)ct * 1024;
                bf16x8 bh = *(const bf16x8*)(blk + l * 8);
                bf16x8 bl = *(const bf16x8*)(blk + 512 + l * 8);
                acc0 = __builtin_amdgcn_mfma_f32_16x16x32_bf16(al0, bh, acc0, 0, 0, 0);
                acc0 = __builtin_amdgcn_mfma_f32_16x16x32_bf16(ah0, bl, acc0, 0, 0, 0);
                acc0 = __builtin_amdgcn_mfma_f32_16x16x32_bf16(ah0, bh, acc0, 0, 0, 0);
                int col = ct * 16 + lr;
                #pragma unroll
                for (int i = 0; i < 4; ++i)
                    myl[(kq * 4 + i) * 128 + col] = (_Float16)acc0[i];
            }
        }
        __syncthreads();
        // ---- phase 2: gather + add + relu + dot W2 over 16 slots ----
        for (int it = 0; it < 8; ++it) {
            int lrow = it * 2 + half;
            int idx = rbase + lrow;
            int4 q4 = ed4[idx];
            int e = q4.x, s = q4.y, d = q4.z, g = q4.w;
            h16x4 As = *(const h16x4*)(ABh + (size_t)s * 256 + 4 * c);
            h16x4 Bd = *(const h16x4*)(ABh + (size_t)d * 256 + 128 + 4 * c);
            h16x4 ew = *(const h16x4*)(myl + lrow * 128 + 4 * c);
            float4 Gg = *(const float4*)(Gp + g * 128 + 4 * c);
            float h0 = fmaxf((float)As[0] + (float)Bd[0] + Gg.x + (float)ew[0], 0.f);
            float h1 = fmaxf((float)As[1] + (float)Bd[1] + Gg.y + (float)ew[1], 0.f);
            float h2 = fmaxf((float)As[2] + (float)Bd[2] + Gg.z + (float)ew[2], 0.f);
            float h3 = fmaxf((float)As[3] + (float)Bd[3] + Gg.w + (float)ew[3], 0.f);
            float r = h0 * w2r.x + h1 * w2r.y + h2 * w2r.z + h3 * w2r.w;
            r += __shfl_xor(r, 1, 64);
            r += __shfl_xor(r, 2, 64);
            r += __shfl_xor(r, 4, 64);
            r += __shfl_xor(r, 8, 64);
            r += __shfl_xor(r, 16, 64);
            if (c == 0) out[e] = r + bias2;
        }
        __syncthreads();
    }
}

// ---------------------------------------------------------------------------
extern "C" void kernel_launch(void* const* d_in, const int* in_sizes, int n_in,
                              void* d_out, int out_size, void* d_ws, size_t ws_size,
                              hipStream_t stream)
{
    const float* x   = (const float*)d_in[0];
    const int* ei    = (const int*)d_in[1];
    const float* ea  = (const float*)d_in[2];
    const int* batch = (const int*)d_in[3];
    const float* Wq1 = (const float*)d_in[4];  const float* bq1 = (const float*)d_in[5];
    const float* Wk1 = (const float*)d_in[6];  const float* bk1 = (const float*)d_in[7];
    const float* Wv1 = (const float*)d_in[8];  const float* bv1 = (const float*)d_in[9];
    const float* We1 = (const float*)d_in[10];
    const float* Ws1 = (const float*)d_in[11]; const float* bs1 = (const float*)d_in[12];
    const float* Wq2 = (const float*)d_in[13]; const float* bq2 = (const float*)d_in[14];
    const float* Wk2 = (const float*)d_in[15]; const float* bk2 = (const float*)d_in[16];
    const float* Wv2 = (const float*)d_in[17]; const float* bv2 = (const float*)d_in[18];
    const float* We2 = (const float*)d_in[19];
    const float* Ws2 = (const float*)d_in[20]; const float* bs2 = (const float*)d_in[21];
    const float* W1  = (const float*)d_in[22]; const float* b1  = (const float*)d_in[23];
    const float* W2  = (const float*)d_in[24]; const float* b2  = (const float*)d_in[25];

    const int* src = ei;
    const int* dst = ei + NE;

    float* ws = (float*)d_ws;
    size_t off = 0;
    float* REG  = ws + off; off += (size_t)NN * 640;  // QSPh -> later ABh
    float* h1   = ws + off; off += (size_t)NN * 128;
    float* h2   = ws + off; off += (size_t)NN * 128;
    float* eac  = ws + off; off += (size_t)NE * 16;
    _Float16* KVh = (_Float16*)(ws + off); off += (size_t)NN * 128;  // N x 256 half
    float* sums = ws + off; off += NG * 128;
    float* cntf = ws + off; off += NG;
    float* Gp   = ws + off; off += NG * 128;
    float* Wp1  = ws + off; off += 64 * 128;
    float* Wp2  = ws + off; off += 128 * 16;
    float* bcat1 = ws + off; off += 640;
    float* bcat2 = ws + off; off += 528;
    __bf16* pk  = (__bf16*)(ws + off); off += 284 * 1024 / 2;  // 284 blocks x 1024 bf16
    int* cnt_arr   = (int*)(ws + off); off += NN;
    int* row_start = (int*)(ws + off); off += NN + 1;
    int* cursor    = (int*)(ws + off); off += NN;
    int* se        = (int*)(ws + off); off += NE;
    int* bsum      = (int*)(ws + off); off += 64;
    off = (off + 3) & ~(size_t)3;                      // 16B align for int4
    int4* ed4      = (int4*)(ws + off); off += (size_t)NE * 4;
    // aliases inside REG:
    _Float16* QSPh = (_Float16*)REG;                   // L1 stride 384 / L2 stride 272
    _Float16* ABh  = (_Float16*)REG;                   // after agg2

    hipMemsetAsync(cnt_arr, 0, NN * sizeof(int), stream);
    hipMemsetAsync(sums, 0, (NG * 128 + NG) * sizeof(float), stream);

    prep_kernel<<<45, 256, 0, stream>>>(Wq1, bq1, bk1, bv1, bs1, We1,
                                        Wq2, bq2, bk2, bv2, bs2, We2,
                                        Wp1, Wp2, bcat1, bcat2);
    pack_kernel<<<284, 256, 0, stream>>>(Wq1, Wk1, Wv1, Ws1, Wp1,
                                         Wq2, Wk2, Wv2, Ws2, Wp2, W1, pk);
    count_kernel<<<(NE + 255) / 256, 256, 0, stream>>>(dst, cnt_arr);
    scanA_kernel<<<SCAN_B, 1024, 0, stream>>>(cnt_arr, row_start, bsum);
    scanC_kernel<<<SCAN_B, 1024, 0, stream>>>(row_start, bsum, cursor);
    scatter_kernel<<<(NE + 255) / 256, 256, 0, stream>>>(src, dst, batch, ea, cursor,
                                                         ed4, se, eac);

    dim3 g1((NN + 127) / 128, 5);
    mfma_gemm_kernel<64, 40, 5, true, 128, 384, 384><<<g1, 256, 0, stream>>>(
        x, pk, bcat1, QSPh, KVh);
    agg1_kernel<<<(NN + 3) / 4, 256, 0, stream>>>(QSPh, KVh, row_start, se, eac, We1, h1);
    dim3 g2((NN + 127) / 128, 6);
    mfma_gemm_kernel<128, 33, 6, true, 128, 384, 272><<<g2, 256, 0, stream>>>(
        h1, pk + (size_t)80 * 1024, bcat2, QSPh, KVh);
    agg2_kernel<<<(NN + 3) / 4, 256, 0, stream>>>(QSPh, KVh, row_start, se, eac, We2, h2);
    pool_kernel<<<(NN + 63) / 64, 256, 0, stream>>>(h2, batch, sums, cntf);
    gp_kernel<<<NG, 128, 0, stream>>>(sums, cntf, W1, b1, Gp);
    dim3 g3((NN + 127) / 128, 2);
    mfma_gemm_kernel<128, 16, 2, false, 0, 256, 0><<<g3, 256, 0, stream>>>(
        h2, pk + (size_t)212 * 1024, nullptr, nullptr, ABh);
    edge_out_kernel<<<NE / 128, 256, 0, stream>>>(ABh, Gp, ed4, eac,
                                                  pk + (size_t)276 * 1024,
                                                  W2, b2, (float*)d_out);
}